// Round 8
// baseline (325.502 us; speedup 1.0000x reference)
//
#include <hip/hip_runtime.h>
#include <cstdint>
#include <cstddef>

#define INPUT_DIM 784
#define HIDDEN    4096
#define BATCH     64
#define T_STEPS   30
#define N0 (BATCH*INPUT_DIM)   // 50176
#define N1 (BATCH*HIDDEN)      // 262144
#define M_ROWS (T_STEPS*BATCH) // 1920
#define NDIG 4
#define MB_CNT (M_ROWS/32)     // 60
#define KC1 25                 // gemm1 k-chunks (784 padded to 800)
#define KC2 128                // gemm2 k-chunks

typedef int v4i  __attribute__((ext_vector_type(4)));
typedef int v16i __attribute__((ext_vector_type(16)));

// ---------------- max(x) reduction (unchanged, passing) --------------------
__global__ __launch_bounds__(256) void max_kernel(const float* __restrict__ x,
                                                  unsigned* __restrict__ maxbits) {
    int i = blockIdx.x * 256 + threadIdx.x;
    float v = (i < N0) ? x[i] : 0.0f;
    #pragma unroll
    for (int off = 32; off > 0; off >>= 1)
        v = fmaxf(v, __shfl_down(v, off, 64));
    __shared__ float sm[4];
    int lane = threadIdx.x & 63;
    int wv   = threadIdx.x >> 6;
    if (lane == 0) sm[wv] = v;
    __syncthreads();
    if (threadIdx.x == 0) {
        float m = fmaxf(fmaxf(sm[0], sm[1]), fmaxf(sm[2], sm[3]));
        atomicMax(maxbits, __float_as_uint(m));
    }
}

// ---------------- layer 0 LIF: same math (passing), spikes -> A-fragments --
// AF1[kc][mb][lane][16], lane=(b&31)|(((j>>4)&1)<<5), mb=2t+(b>>5), byte=j&15.
__global__ __launch_bounds__(256) void lif0_kernel(const float* __restrict__ x,
                                                   const unsigned* __restrict__ maxbits,
                                                   uint8_t* __restrict__ AF1,
                                                   float* __restrict__ out0) {
    int j = blockIdx.x * 256 + threadIdx.x;   // input-dim index
    int b = blockIdx.y;                        // batch
    if (j >= INPUT_DIM) return;
    float mx = fmaxf(__uint_as_float(*maxbits), 1e-12f);
    float xs = __fmul_rn(__fdiv_rn(x[b * INPUT_DIM + j], mx), 16.0f);
    int kc = j >> 5;
    int lane = (b & 31) | (((j >> 4) & 1) << 5);
    size_t base = (((size_t)(kc * MB_CNT + (b >> 5)) * 64 + lane) << 4) + (j & 15);
    float v = 0.0f;
    int cnt = 0;
    #pragma unroll
    for (int t = 0; t < T_STEPS; ++t) {
        v = __fadd_rn(__fmul_rn(v, 0.99f), xs);
        int s = (v >= 0.5f) ? 1 : 0;
        cnt += s;
        v = s ? 0.0f : v;
        AF1[base + (size_t)t * 2048] = (uint8_t)s;
    }
    out0[b * INPUT_DIM + j] = (float)cnt / 30.0f;
}

// ---------------- W -> 4 digit planes in MFMA B-fragment order -------------
// q = round(W * scale); 4 signed base-256 digits; per-elem err <= 1/(2*scale).
// BF[nb][kc][d][lane][16]; rows k >= Krows are zero (gemm1 K padding).
__global__ __launch_bounds__(256) void digitize_kernel(const float* __restrict__ W,
                                                       int8_t* __restrict__ BF,
                                                       int Krows, int KC, double scale) {
    __shared__ float tile[32][33];
    const int nb = blockIdx.x, kc = blockIdx.y;
    const int tid = threadIdx.x;
    {
        int r  = tid >> 3;
        int c4 = (tid & 7) << 2;
        int k  = kc * 32 + r;
        float4 w4 = make_float4(0.f, 0.f, 0.f, 0.f);
        if (k < Krows)
            w4 = *(const float4*)&W[(size_t)k * HIDDEN + nb * 32 + c4];
        tile[r][c4]     = w4.x;
        tile[r][c4 + 1] = w4.y;
        tile[r][c4 + 2] = w4.z;
        tile[r][c4 + 3] = w4.w;
    }
    __syncthreads();
    const int d    = tid >> 6;        // wave -> digit plane
    const int lane = tid & 63;
    const int nl   = lane & 31;
    const int kh   = (lane >> 5) << 4;
    char dig[16];
    #pragma unroll
    for (int jj = 0; jj < 16; ++jj) {
        double w = (double)tile[kh + jj][nl];
        long long q = __double2ll_rn(w * scale);
        int dd = 0;
        #pragma unroll
        for (int dd_i = 0; dd_i <= 3; ++dd_i) {
            dd = (int)(((q + 128) & 255) - 128);
            q = (q - (long long)dd) >> 8;
            if (dd_i == d) break;
        }
        dig[jj] = (char)dd;
    }
    *(int4*)&BF[((((size_t)nb * KC + kc) * NDIG + d) << 10) + (lane << 4)] =
        *(int4*)&dig[0];
}

// ---------------- exact i8-digit streaming GEMM (both layers) --------------
// C(1920 x 4096 f64) = A(binary) @ W, 4 digit planes. R8: TWO K-CHUNKS PER
// BARRIER (ring-3 x 24KB pair-buffers) + setprio around the MFMA cluster.
//
// R7 post-mortem: decoupling ds_reads from MFMA was NEUTRAL -> overlap was
// already fine. Wall 1100 cyc/iter vs MFMA 585 + LDS-port ~565 (at the real
// ~128 B/cyc port rate) -> the ~500 residual is PER-BARRIER sync cost (all-
// wave rendezvous + counted-vmcnt wait each chunk; m233's 2-phase stall).
// R8 amortizes it: one barrier per TWO chunks (1170 cyc of MFMA between
// barriers), setprio(1) on the MFMA cluster so compute waves win arbitration.
//
// Structure: pair-iter j covers chunks 2j,2j+1 in buf j%3 (24KB: two 12KB
// sub-bufs, each {A 4K | B-nb0 4K | B-nb1 4K} as in R5). After the barrier:
// read 12 frags, stage pair j+2 into buf (j+2)%3 (6 gloads/thread), 16 MFMA.
// Safety: write-buf (j+2)%3 = read-buf of iter j-1; those reads completed
// before MFMA(j-1) (data dep) which precedes barrier(j) for every wave ->
// no write-before-read. In-flight gloads (pair j+1, issued iter j-1) target
// buf (j+1)%3, disjoint from read and write bufs.
// vmcnt ledger (6 gloads/pair-stage, in-order retire): at barrier(j) in
// flight = {pair j (issued j-2), pair j+1 (issued j-1)} = 12 -> retire pair
// j = vmcnt(6). KC=128 (P=64): main j=0..61, tails j=62 vmcnt(6), j=63
// vmcnt(0). KC=25 (P=12+1): main j=0..9; j=10 vmcnt(6) + STAGE1(c24->buf0
// sub0, 3 gloads; buf0 last read j=9); j=11 vmcnt(3) [in flight pair11(6)+
// c24(3)=9, retire pair11]; j=12 vmcnt(0), single-chunk MFMA.
#define MFMA_GRP(A0, A1, B0, B1, B2, B3)                                        \
    acc[0][0] = __builtin_amdgcn_mfma_i32_32x32x32_i8(A0, B0, acc[0][0], 0, 0, 0); \
    acc[1][0] = __builtin_amdgcn_mfma_i32_32x32x32_i8(A1, B0, acc[1][0], 0, 0, 0); \
    acc[0][1] = __builtin_amdgcn_mfma_i32_32x32x32_i8(A0, B1, acc[0][1], 0, 0, 0); \
    acc[1][1] = __builtin_amdgcn_mfma_i32_32x32x32_i8(A1, B1, acc[1][1], 0, 0, 0); \
    acc[0][2] = __builtin_amdgcn_mfma_i32_32x32x32_i8(A0, B2, acc[0][2], 0, 0, 0); \
    acc[1][2] = __builtin_amdgcn_mfma_i32_32x32x32_i8(A1, B2, acc[1][2], 0, 0, 0); \
    acc[0][3] = __builtin_amdgcn_mfma_i32_32x32x32_i8(A0, B3, acc[0][3], 0, 0, 0); \
    acc[1][3] = __builtin_amdgcn_mfma_i32_32x32x32_i8(A1, B3, acc[1][3], 0, 0, 0)

__device__ __forceinline__ void gload16(const int8_t* g, int8_t* l) {
    __builtin_amdgcn_global_load_lds(
        (const __attribute__((address_space(1))) void*)g,
        (__attribute__((address_space(3))) void*)l, 16, 0, 0);
}

// stage ONE chunk (running pointers) into a 12KB sub-buffer; advance 1 chunk.
#define STAGE1(SUBP)                                                             \
    do {                                                                         \
        int8_t* sb_ = (SUBP);                                                    \
        gload16(spA,  sb_ +        (wave << 10));                                \
        gload16(spB0, sb_ + 4096 + (wave << 10));                                \
        gload16(spB1, sb_ + 8192 + (wave << 10));                                \
        spA += astride; spB0 += bstride; spB1 += bstride;                        \
    } while (0)

// stage a PAIR of chunks into buf BUF (sub0 then sub1): 6 gloads/thread.
#define STAGE2(BUF)                                                              \
    do {                                                                         \
        STAGE1(&lds[BUF][0]);                                                    \
        STAGE1(&lds[BUF][12288]);                                                \
    } while (0)

// read one chunk's 6 fragments from a 12KB sub-buffer at byte offset SOFF.
#define READ_FRAGS(BUF, SOFF, A0, A1, B0, B1, B2, B3)                            \
    A0 = *(const v4i*)&lds[BUF][(SOFF) +  msb      * 1024 + (lane << 4)];        \
    A1 = *(const v4i*)&lds[BUF][(SOFF) + (msb + 1) * 1024 + (lane << 4)];        \
    B0 = *(const v4i*)&lds[BUF][(SOFF) + 4096 + ((wave & 1) << 12) +        (lane << 4)]; \
    B1 = *(const v4i*)&lds[BUF][(SOFF) + 4096 + ((wave & 1) << 12) + 1024 + (lane << 4)]; \
    B2 = *(const v4i*)&lds[BUF][(SOFF) + 4096 + ((wave & 1) << 12) + 2048 + (lane << 4)]; \
    B3 = *(const v4i*)&lds[BUF][(SOFF) + 4096 + ((wave & 1) << 12) + 3072 + (lane << 4)]

#define WAITBAR(WN)                                                              \
    __builtin_amdgcn_sched_barrier(0);                                           \
    asm volatile("s_waitcnt vmcnt(" #WN ")\n\ts_barrier" ::: "memory");          \
    __builtin_amdgcn_sched_barrier(0)

// one pair-iteration: barrier round, read both chunks' frags, stage SCODE,
// 16 MFMAs (chunk-a then chunk-b; 8 independent acc chains of length 2)
// wrapped in setprio(1) (T5: compute waves win CU arbitration).
#define ITER2(BUF, WN, SCODE)                                                    \
    do {                                                                         \
        WAITBAR(WN);                                                             \
        v4i xa0, xa1, xb0, xb1, xb2, xb3, ya0, ya1, yb0, yb1, yb2, yb3;          \
        READ_FRAGS(BUF, 0,     xa0, xa1, xb0, xb1, xb2, xb3);                    \
        READ_FRAGS(BUF, 12288, ya0, ya1, yb0, yb1, yb2, yb3);                    \
        SCODE;                                                                   \
        __builtin_amdgcn_s_setprio(1);                                           \
        MFMA_GRP(xa0, xa1, xb0, xb1, xb2, xb3);                                  \
        MFMA_GRP(ya0, ya1, yb0, yb1, yb2, yb3);                                  \
        __builtin_amdgcn_s_setprio(0);                                           \
    } while (0)

template <int KC>
__global__ __launch_bounds__(256, 2) void gemm_i8_kernel(const int8_t* __restrict__ AF,
                                                         const int8_t* __restrict__ BF,
                                                         double* __restrict__ C,
                                                         double scale) {
    __shared__ int8_t lds[3][24576];        // 72 KB/block, 2 blocks = 144/160
    const int tid  = threadIdx.x;
    const int wave = tid >> 6, lane = tid & 63;
    const int i  = blockIdx.x;
    // phase-grouped XCD mapping (R3): two dispatch phases of 480; per phase
    // each XCD owns 4 by-windows = 4MB of B (L2-resident).
    const int p  = (i >= 480) ? 1 : 0;
    const int j  = i - p * 480;
    const int bx = j >> 5;                                   // 0..14
    const int by = p * 32 + ((j & 7) << 2) + ((j >> 3) & 3); // 0..63
    const int nb0 = by * 2;
    const int msb = (wave >> 1) * 2;

    const int astride = MB_CNT * 1024;      // 61440 B per k-chunk in AF
    const int bstride = NDIG * 1024;        // 4096  B per k-chunk in BF panel
    // per-thread 16B staging sources (tid*16 = wave*1024 + lane*16)
    const int8_t* spA  = AF + (((size_t)(bx * 4) * 64) << 4) + tid * 16;
    const int8_t* spB0 = BF + (((size_t)nb0 * KC * NDIG) << 10) + tid * 16;
    const int8_t* spB1 = spB0 + ((size_t)KC * NDIG << 10);

    v16i acc[2][4] = {};

    STAGE2(0);                              // chunks 0,1 -> buf 0
    STAGE2(1);                              // chunks 2,3 -> buf 1

    constexpr int P  = KC / 2;              // 64 pairs (KC=128), 12 (KC=25)
    constexpr int PM = P - 2;               // staged main pairs: 62, 10
    constexpr int G  = PM / 3, R = PM % 3;  // 128: 20,2 ; 25: 3,1
    for (int g = 0; g < G; ++g) {
        ITER2(0, 6, STAGE2(2));
        ITER2(1, 6, STAGE2(0));
        ITER2(2, 6, STAGE2(1));
    }
    if constexpr (R == 2) {                 // KC=128: pairs 60,61 then tails
        ITER2(0, 6, STAGE2(2));             // pair 60, stage pair 62
        ITER2(1, 6, STAGE2(0));             // pair 61, stage pair 63 (c126,127)
        ITER2(2, 6, );                      // pair 62
        ITER2(0, 0, );                      // pair 63
    } else if constexpr (R == 1) {          // KC=25: pair 9, then odd tail
        ITER2(0, 6, STAGE2(2));             // pair 9, stage pair 11 (c22,23)
        ITER2(1, 6, STAGE1(&lds[0][0]));    // pair 10, stage c24 -> buf0 sub0
        ITER2(2, 3, );                      // pair 11 (retire its 6, keep c24's 3)
        {                                   // chunk 24 alone
            WAITBAR(0);
            v4i za0, za1, zb0, zb1, zb2, zb3;
            READ_FRAGS(0, 0, za0, za1, zb0, zb1, zb2, zb3);
            __builtin_amdgcn_s_setprio(1);
            MFMA_GRP(za0, za1, zb0, zb1, zb2, zb3);
            __builtin_amdgcn_s_setprio(0);
        }
    } else {
        ITER2(0, 6, );
        ITER2(1, 0, );
    }

    // epilogue: C/D layout col=lane&31, row=(r&3)+8*(r>>2)+4*(lane>>5)
    const int col = lane & 31;
    const int rb  = (lane >> 5) << 2;
    const int n_g = by * 64 + (wave & 1) * 32 + col;
    #pragma unroll
    for (int s = 0; s < 2; ++s) {
        const int m_base = bx * 128 + (msb + s) * 32;
        #pragma unroll
        for (int r = 0; r < 16; ++r) {
            int row = (r & 3) + 8 * (r >> 2) + rb;
            long long v = 0;
            #pragma unroll
            for (int d = 3; d >= 0; --d) v = (v << 8) + (long long)acc[s][d][r];
            C[(size_t)(m_base + row) * HIDDEN + n_g] = (double)v * scale;
        }
    }
}

// ---------------- layer 1 LIF: f64 currents, spikes -> A-fragments ---------
__global__ __launch_bounds__(256) void lif1_kernel(const double* __restrict__ CUR,
                                                   uint8_t* __restrict__ AF,
                                                   float* __restrict__ out1) {
    int e = blockIdx.x * 256 + threadIdx.x;
    int b = e >> 12;
    int j = e & 4095;
    int kc = j >> 5;
    int lane = (b & 31) | (((j >> 4) & 1) << 5);
    size_t base = (((size_t)(kc * MB_CNT + (b >> 5)) * 64 + lane) << 4) + (j & 15);
    double v = 0.0;
    int cnt = 0;
    #pragma unroll
    for (int t = 0; t < T_STEPS; ++t) {
        double cur = CUR[(size_t)t * N1 + e];
        v = __dadd_rn(__dmul_rn(v, 0.99), cur);
        int s = (v >= 0.5) ? 1 : 0;
        cnt += s;
        v = s ? 0.0 : v;
        AF[base + (size_t)t * 2048] = (uint8_t)s;
    }
    out1[e] = (float)cnt / 30.0f;
}

// ---------------- layer 2 LIF in fp64 (unchanged, passing) -----------------
__global__ __launch_bounds__(256) void lif2_kernel(const double* __restrict__ CUR,
                                                   float* __restrict__ out2) {
    int e = blockIdx.x * 256 + threadIdx.x;
    double v = 0.0;
    int cnt = 0;
    #pragma unroll
    for (int t = 0; t < T_STEPS; ++t) {
        double cur = CUR[(size_t)t * N1 + e];
        v = __dadd_rn(__dmul_rn(v, 0.99), cur);
        int s = (v >= 0.5) ? 1 : 0;
        cnt += s;
        v = s ? 0.0 : v;
    }
    out2[e] = (float)cnt / 30.0f;
}

extern "C" void kernel_launch(void* const* d_in, const int* in_sizes, int n_in,
                              void* d_out, int out_size, void* d_ws, size_t ws_size,
                              hipStream_t stream) {
    const float* x  = (const float*)d_in[0];
    const float* W1 = (const float*)d_in[1];   // 784 x 4096
    const float* W2 = (const float*)d_in[2];   // 4096 x 4096
    float* out = (float*)d_out;
    char*  ws  = (char*)d_ws;

    // workspace (~153 MB):
    // [maxbits 256B][AF1 1.54MB][BF1 12.8MB][AF2 7.86MB][BF2 64MB][CURd 62.9MB]
    const size_t AF1_SZ = (size_t)KC1 * MB_CNT * 1024;           // 1,536,000
    const size_t BF1_SZ = (size_t)128 * KC1 * NDIG * 1024;       // 12.8 MB
    const size_t AF2_SZ = (size_t)KC2 * MB_CNT * 1024;           // 7.86 MB
    const size_t BF2_SZ = (size_t)128 * KC2 * NDIG * 1024;       // 64 MB
    unsigned* maxbits = (unsigned*)ws;
    uint8_t*  AF1 = (uint8_t*)(ws + 256);
    int8_t*   BF1 = (int8_t*)(AF1 + AF1_SZ);
    uint8_t*  AF2 = (uint8_t*)(BF1 + BF1_SZ);
    int8_t*   BF2 = (int8_t*)(AF2 + AF2_SZ);
    double*   CURd = (double*)((char*)BF2 + BF2_SZ);

    float* out0 = out;
    float* out1 = out + N0;
    float* out2 = out + N0 + N1;

    hipMemsetAsync(maxbits, 0, 4, stream);
    hipMemsetAsync(AF1, 0, AF1_SZ, stream);   // K-padding rows 784..799 stay 0
    max_kernel <<<(N0 + 255) / 256, 256, 0, stream>>>(x, maxbits);
    lif0_kernel<<<dim3(4, BATCH), 256, 0, stream>>>(x, maxbits, AF1, out0);
    digitize_kernel<<<dim3(128, KC1), 256, 0, stream>>>(W1, BF1, INPUT_DIM, KC1,
                                                        4294967296.0);      // 2^32
    digitize_kernel<<<dim3(128, KC2), 256, 0, stream>>>(W2, BF2, HIDDEN, KC2,
                                                        8589934592.0);      // 2^33
    gemm_i8_kernel<KC1><<<960, 256, 0, stream>>>((const int8_t*)AF1, BF1, CURd,
                                                 2.3283064365386963e-10);   // 2^-32
    lif1_kernel<<<N1 / 256, 256, 0, stream>>>(CURd, AF2, out1);
    gemm_i8_kernel<KC2><<<960, 256, 0, stream>>>((const int8_t*)AF2, BF2, CURd,
                                                 1.1641532182693481e-10);   // 2^-33
    lif2_kernel<<<N1 / 256, 256, 0, stream>>>(CURd, out2);
}